// Round 3
// baseline (362.504 us; speedup 1.0000x reference)
//
#include <hip/hip_runtime.h>

#define LDIM 320
#define CZ 128
#define NH 4
#define CH 32
// SCALE * log2(e): softmax runs in exp2 domain
#define SCALE2F (0.17677669529663687f * 1.4426950408889634f)
#define LOG2E 1.4426950408889634f
#define LN_EPS 1e-5f

typedef __attribute__((ext_vector_type(8))) short bf16x8;
typedef __attribute__((ext_vector_type(4))) float f32x4;

__device__ __forceinline__ unsigned int pack_bf2(float a, float b) {
  unsigned int ua = __float_as_uint(a);
  unsigned int ub = __float_as_uint(b);
  unsigned int ra = (ua + 0x7fffu + ((ua >> 16) & 1u)) >> 16;   // RNE bf16
  unsigned int rb = (ub + 0x7fffu + ((ub >> 16) & 1u)) >> 16;
  return (ra & 0xffffu) | (rb << 16);
}

__device__ __forceinline__ unsigned short f2bf(float a) {
  unsigned int ua = __float_as_uint(a);
  return (unsigned short)((ua + 0x7fffu + ((ua >> 16) & 1u)) >> 16);
}

__device__ __forceinline__ float bf2f(unsigned short u) {
  return __uint_as_float(((unsigned int)u) << 16);
}

// v_cvt_pk_bf16_f32: lo16 = bf16(a), hi16 = bf16(b), RNE (no builtin on gfx950)
__device__ __forceinline__ unsigned cvtpk(float a, float b) {
  unsigned r;
  asm("v_cvt_pk_bf16_f32 %0, %1, %2" : "=v"(r) : "v"(a), "v"(b));
  return r;
}

// v_permlane32_swap_b32: a.lanes[32..63] <-> b.lanes[0..31]
// After: a = [a.lo | b.lo], b = [a.hi | b.hi]
__device__ __forceinline__ void plswap(unsigned& a, unsigned& b) {
  asm volatile("v_permlane32_swap_b32 %0, %1" : "+v"(a), "+v"(b));
}

// ---------------------------------------------------------------------------
// Kernel 0: weight prep. Wt[576][128] bf16 = [Wq|Wk|Wv|Wg|Wb|0] transposed;
// Woutt[128][128] bf16 = Wout transposed. Runs once per launch (11 blocks).
// ---------------------------------------------------------------------------
__global__ __launch_bounds__(256) void k_prep(
    const float* __restrict__ Wq, const float* __restrict__ Wk,
    const float* __restrict__ Wv, const float* __restrict__ Wb,
    const float* __restrict__ Wg, const float* __restrict__ Wout,
    unsigned short* __restrict__ Wt, unsigned short* __restrict__ Woutt)
{
  __shared__ __attribute__((aligned(16))) unsigned short buf[64 * 136];
  const int t = threadIdx.x, bid = blockIdx.x;
  const bool isOut = (bid >= 9);
  const int n0 = isOut ? (bid - 9) * 64 : bid * 64;
  const int nl = t & 63;
  const int n = n0 + nl;
#pragma unroll 8
  for (int it = 0; it < 32; ++it) {
    const int k = (t >> 6) + 4 * it;
    float v;
    if (isOut)        v = Wout[k * 128 + n];
    else if (n < 128) v = Wq[k * 128 + n];
    else if (n < 256) v = Wk[k * 128 + n - 128];
    else if (n < 384) v = Wv[k * 128 + n - 256];
    else if (n < 512) v = Wg[k * 128 + n - 384];
    else if (n < 516) v = Wb[k * 4 + n - 512];
    else              v = 0.f;
    buf[nl * 136 + k] = f2bf(v);
  }
  __syncthreads();
  unsigned short* dst = isOut ? Woutt : Wt;
#pragma unroll
  for (int it = 0; it < 4; ++it) {
    const int idx = t + 256 * it;
    const int rr = idx >> 4, ck = idx & 15;
    const uint4 d = *(const uint4*)&buf[rr * 136 + ck * 8];
    *(uint4*)(dst + (size_t)(n0 + rr) * 128 + ck * 8) = d;
  }
}

// ---------------------------------------------------------------------------
// Kernel 1: fused LayerNorm + all projections, bf16 MFMA GEMM.
// Bh stores bias * log2(e) + (res_mask ? 0 : -inf).
// This round: B-tile rows re-indexed as n = ntile*64 + m16*4 + nt so each
// thread's 4 nt-outputs are consecutive channels -> one uint2 store
// (was 4 scalar u16 stores). Pure re-labeling; Wt unchanged.
// ---------------------------------------------------------------------------
__global__ __launch_bounds__(256) void k_lnproj(
    const float* __restrict__ z, const float* __restrict__ gamma,
    const float* __restrict__ beta, const unsigned short* __restrict__ Wt,
    const int* __restrict__ rmask,
    unsigned short* __restrict__ Qg, unsigned short* __restrict__ Kg,
    unsigned short* __restrict__ Vg, unsigned short* __restrict__ Gg,
    float* __restrict__ Bh)
{
  __shared__ __attribute__((aligned(16))) unsigned short As[128 * 136]; // 34.8KB
  const int t = threadIdx.x;
  const int m0 = blockIdx.x * 128;
  const int rlane = t & 7;            // 8 lanes per row, 16 cols each

  const float* gp = gamma + rlane * 16;
  const float* bp = beta + rlane * 16;
  const float4 g0 = *(const float4*)(gp + 0);
  const float4 g1 = *(const float4*)(gp + 4);
  const float4 g2 = *(const float4*)(gp + 8);
  const float4 g3 = *(const float4*)(gp + 12);
  const float4 b0 = *(const float4*)(bp + 0);
  const float4 b1 = *(const float4*)(bp + 4);
  const float4 b2 = *(const float4*)(bp + 8);
  const float4 b3 = *(const float4*)(bp + 12);

  // ---- stage z -> LN -> bf16 As, coalesced (8 lanes/row) ----
#pragma unroll
  for (int rr = 0; rr < 4; ++rr) {
    const int row = rr * 32 + (t >> 3);
    const float* zp = z + (size_t)(m0 + row) * CZ + rlane * 16;
    const float4 x0 = *(const float4*)(zp + 0);
    const float4 x1 = *(const float4*)(zp + 4);
    const float4 x2 = *(const float4*)(zp + 8);
    const float4 x3 = *(const float4*)(zp + 12);
    float s  = x0.x + x0.y + x0.z + x0.w + x1.x + x1.y + x1.z + x1.w +
               x2.x + x2.y + x2.z + x2.w + x3.x + x3.y + x3.z + x3.w;
    float ss = x0.x*x0.x + x0.y*x0.y + x0.z*x0.z + x0.w*x0.w +
               x1.x*x1.x + x1.y*x1.y + x1.z*x1.z + x1.w*x1.w +
               x2.x*x2.x + x2.y*x2.y + x2.z*x2.z + x2.w*x2.w +
               x3.x*x3.x + x3.y*x3.y + x3.z*x3.z + x3.w*x3.w;
    s  += __shfl_xor(s, 1);  ss += __shfl_xor(ss, 1);
    s  += __shfl_xor(s, 2);  ss += __shfl_xor(ss, 2);
    s  += __shfl_xor(s, 4);  ss += __shfl_xor(ss, 4);
    const float mu  = s * (1.f / 128.f);
    const float var = ss * (1.f / 128.f) - mu * mu;
    const float rs  = rsqrtf(var + LN_EPS);
    uint4 u0, u1;
    u0.x = pack_bf2((x0.x - mu) * rs * g0.x + b0.x, (x0.y - mu) * rs * g0.y + b0.y);
    u0.y = pack_bf2((x0.z - mu) * rs * g0.z + b0.z, (x0.w - mu) * rs * g0.w + b0.w);
    u0.z = pack_bf2((x1.x - mu) * rs * g1.x + b1.x, (x1.y - mu) * rs * g1.y + b1.y);
    u0.w = pack_bf2((x1.z - mu) * rs * g1.z + b1.z, (x1.w - mu) * rs * g1.w + b1.w);
    u1.x = pack_bf2((x2.x - mu) * rs * g2.x + b2.x, (x2.y - mu) * rs * g2.y + b2.y);
    u1.y = pack_bf2((x2.z - mu) * rs * g2.z + b2.z, (x2.w - mu) * rs * g2.w + b2.w);
    u1.z = pack_bf2((x3.x - mu) * rs * g3.x + b3.x, (x3.y - mu) * rs * g3.y + b3.y);
    u1.w = pack_bf2((x3.z - mu) * rs * g3.z + b3.z, (x3.w - mu) * rs * g3.w + b3.w);
    unsigned short* dst = &As[row * 136 + rlane * 16];
    *(uint4*)(dst + 0) = u0;
    *(uint4*)(dst + 8) = u1;
  }
  __syncthreads();

  const int w = t >> 6, lane = t & 63;
  const int m16 = lane & 15, qd = lane >> 4;
  const f32x4 z4 = {0.f, 0.f, 0.f, 0.f};

  // ---- preload A-frags once (2 sub-tiles x 4 k-steps = 32 VGPRs) ----
  bf16x8 af[2][4];
#pragma unroll
  for (int ks = 0; ks < 4; ++ks) {
    af[0][ks] = *(const bf16x8*)&As[(w * 32 + m16) * 136 + ks * 32 + qd * 8];
    af[1][ks] = *(const bf16x8*)&As[(w * 32 + 16 + m16) * 136 + ks * 32 + qd * 8];
  }

  // ---- 8 output n-tiles (Q/K/V/G); B rows n = ntile*64 + m16*4 + nt ----
  for (int ntile = 0; ntile < 8; ++ntile) {
    f32x4 acc[2][4];
#pragma unroll
    for (int sub = 0; sub < 2; ++sub)
#pragma unroll
      for (int nt = 0; nt < 4; ++nt) acc[sub][nt] = z4;
#pragma unroll
    for (int ks = 0; ks < 4; ++ks) {
#pragma unroll
      for (int nt = 0; nt < 4; ++nt) {
        const bf16x8 bf = *(const bf16x8*)(
            Wt + (size_t)(ntile * 64 + m16 * 4 + nt) * 128 + ks * 32 + qd * 8);
        acc[0][nt] = __builtin_amdgcn_mfma_f32_16x16x32_bf16(af[0][ks], bf, acc[0][nt], 0, 0, 0);
        acc[1][nt] = __builtin_amdgcn_mfma_f32_16x16x32_bf16(af[1][ks], bf, acc[1][nt], 0, 0, 0);
      }
    }
    // epilogue: thread (sub,r) owns 4 consecutive channels cc0..cc0+3
    const int cc0 = (m16 * 4) & 31;
    const int hh = (ntile & 1) * 2 + (m16 >> 3);
    unsigned short* dstb =
        (ntile < 2 ? Qg : (ntile < 4 ? Kg : (ntile < 6 ? Vg : Gg)));
#pragma unroll
    for (int sub = 0; sub < 2; ++sub) {
#pragma unroll
      for (int r = 0; r < 4; ++r) {
        const int p = m0 + w * 32 + sub * 16 + qd * 4 + r;
        const int a = p / 320, bb = p - a * 320;
        float v0 = acc[sub][0][r], v1 = acc[sub][1][r];
        float v2 = acc[sub][2][r], v3 = acc[sub][3][r];
        if (ntile >= 6) {
          v0 = 1.f / (1.f + __expf(-v0));
          v1 = 1.f / (1.f + __expf(-v1));
          v2 = 1.f / (1.f + __expf(-v2));
          v3 = 1.f / (1.f + __expf(-v3));
        }
        uint2 pk;
        pk.x = pack_bf2(v0, v1);
        pk.y = pack_bf2(v2, v3);
        *(uint2*)(dstb + ((size_t)(a * 4 + hh) * 320 + bb) * 32 + cc0) = pk;
      }
    }
  }

  // ---- bias tile: store log2e-scaled bias with res_mask folded in ----
  {
    f32x4 acc0 = z4, acc1 = z4;
#pragma unroll
    for (int ks = 0; ks < 4; ++ks) {
      const bf16x8 bf = *(const bf16x8*)(
          Wt + (size_t)(512 + m16) * 128 + ks * 32 + qd * 8);
      acc0 = __builtin_amdgcn_mfma_f32_16x16x32_bf16(af[0][ks], bf, acc0, 0, 0, 0);
      acc1 = __builtin_amdgcn_mfma_f32_16x16x32_bf16(af[1][ks], bf, acc1, 0, 0, 0);
    }
    if (m16 < 4) {
#pragma unroll
      for (int r = 0; r < 4; ++r) {
        const int p0 = m0 + w * 32 + qd * 4 + r;
        const int p1 = p0 + 16;
        const float mk0 = rmask[p0 % 320] ? 0.f : -INFINITY;
        const float mk1 = rmask[p1 % 320] ? 0.f : -INFINITY;
        Bh[(size_t)m16 * 102400 + p0] = acc0[r] * LOG2E + mk0;
        Bh[(size_t)m16 * 102400 + p1] = acc1[r] * LOG2E + mk1;
      }
    }
  }
}

// ---------------------------------------------------------------------------
// Kernel 2: MFMA attention — register-space P transpose, no Ps LDS.
// Swapped QK^T (acc = mfma(K, Q)): lane (qd,m16) holds S[k=kt*16+qd*4+r][j=m16].
// Softmax reduce: in-lane + shfl_xor(16,32). Bias: one float4 per kt.
// P -> A-frag: cvt_pk pairs, then per K-slot one permlane32_swap pair-trick
// + 2 shfl_xor(16) + cndmask selects (derivation in session notes):
//   A=W[2ks](even kt), B=W[2ks+1](odd kt); after swap A'=[A.lo|B.lo],
//   B'=[A.hi|B.hi]; word_gA = odd(qd)? sw16(B'):A'; word_gB = odd(qd)? B':sw16(A').
// ---------------------------------------------------------------------------
__global__ __launch_bounds__(256) void k_attn(
    const unsigned short* __restrict__ Qg, const unsigned short* __restrict__ Kg,
    const unsigned short* __restrict__ Vg, const unsigned short* __restrict__ Gg,
    const float* __restrict__ Bh, unsigned short* __restrict__ Obg)
{
  __shared__ __attribute__((aligned(16))) unsigned short Vt[32 * 328];  // [c][k] 21KB
  const int h = blockIdx.x, i = blockIdx.y;
  const int t = threadIdx.x;
  const size_t base = (size_t)(i * NH + h) * (LDIM * CH);

  // ---- stage V transposed [c][k] ----
  {
    const int k0 = t >> 3, c4 = (t & 7) * 4;
#pragma unroll
    for (int it = 0; it < 10; ++it) {
      const int k = k0 + 32 * it;
      const uint2 d = *(const uint2*)(Vg + base + k * 32 + c4);
      Vt[(c4 + 0) * 328 + k] = (unsigned short)(d.x & 0xffffu);
      Vt[(c4 + 1) * 328 + k] = (unsigned short)(d.x >> 16);
      Vt[(c4 + 2) * 328 + k] = (unsigned short)(d.y & 0xffffu);
      Vt[(c4 + 3) * 328 + k] = (unsigned short)(d.y >> 16);
    }
  }
  __syncthreads();   // only barrier in the kernel

  const int w = t >> 6, lane = t & 63;
  const int m16 = lane & 15, qd = lane >> 4;
  const int odd = qd & 1;
  const f32x4 z4 = {0.f, 0.f, 0.f, 0.f};

  for (int jt = w; jt < 20; jt += 4) {
    const bf16x8 qfrag =
        *(const bf16x8*)(Qg + base + (size_t)(jt * 16 + m16) * 32 + qd * 8);

    f32x4 acc[20];
    __builtin_amdgcn_s_setprio(1);
#pragma unroll
    for (int kt = 0; kt < 20; ++kt) {
      const bf16x8 kf =
          *(const bf16x8*)(Kg + base + (size_t)(kt * 16 + m16) * 32 + qd * 8);
      acc[kt] = __builtin_amdgcn_mfma_f32_16x16x32_bf16(kf, qfrag, z4, 0, 0, 0);
    }
    __builtin_amdgcn_s_setprio(0);

    // Bh holds bias*log2e + mask(-inf); lane needs row j=jt*16+m16,
    // k = kt*16 + qd*4 + r -> one float4 per kt.
    const float* bq = Bh + (size_t)h * 102400 +
                      (size_t)(jt * 16 + m16) * 320 + qd * 4;
    float mxa = -INFINITY, mxb = -INFINITY;
#pragma unroll
    for (int kt = 0; kt < 20; ++kt) {
      const float4 bv = *(const float4*)(bq + kt * 16);
      const float s0 = fmaf(acc[kt][0], SCALE2F, bv.x);
      const float s1 = fmaf(acc[kt][1], SCALE2F, bv.y);
      const float s2 = fmaf(acc[kt][2], SCALE2F, bv.z);
      const float s3 = fmaf(acc[kt][3], SCALE2F, bv.w);
      acc[kt][0] = s0; acc[kt][1] = s1; acc[kt][2] = s2; acc[kt][3] = s3;
      mxa = fmaxf(mxa, fmaxf(s0, s1));
      mxb = fmaxf(mxb, fmaxf(s2, s3));
    }
    float mx = fmaxf(mxa, mxb);
    mx = fmaxf(mx, __shfl_xor(mx, 16));
    mx = fmaxf(mx, __shfl_xor(mx, 32));

    float l0 = 0.f, l1 = 0.f, l2 = 0.f, l3 = 0.f;
#pragma unroll
    for (int kt = 0; kt < 20; ++kt) {
      const float p0 = __builtin_amdgcn_exp2f(acc[kt][0] - mx);
      const float p1 = __builtin_amdgcn_exp2f(acc[kt][1] - mx);
      const float p2 = __builtin_amdgcn_exp2f(acc[kt][2] - mx);
      const float p3 = __builtin_amdgcn_exp2f(acc[kt][3] - mx);
      acc[kt][0] = p0; acc[kt][1] = p1; acc[kt][2] = p2; acc[kt][3] = p3;
      l0 += p0; l1 += p1; l2 += p2; l3 += p3;
    }
    float l = (l0 + l1) + (l2 + l3);
    l += __shfl_xor(l, 16);
    l += __shfl_xor(l, 32);
    const float rl = __builtin_amdgcn_rcpf(l);
    // redistribute: epilogue row j = jt*16 + qd*4 + r needs rl of that column
    float rle[4];
#pragma unroll
    for (int r = 0; r < 4; ++r) rle[r] = __shfl(rl, qd * 4 + r);

    f32x4 accO0 = z4, accO1 = z4;
#pragma unroll
    for (int hh = 0; hh < 2; ++hh) {
      // pack P~ (f32 -> bf16 pairs): Wl = k-offsets {0,1}, Wh = {2,3}
      unsigned Wl[10], Wh[10];
#pragma unroll
      for (int kr = 0; kr < 10; ++kr) {
        Wl[kr] = cvtpk(acc[hh * 10 + kr][0], acc[hh * 10 + kr][1]);
        Wh[kr] = cvtpk(acc[hh * 10 + kr][2], acc[hh * 10 + kr][3]);
      }
      __builtin_amdgcn_s_setprio(1);
#pragma unroll
      for (int ks = 0; ks < 5; ++ks) {
        unsigned a0 = Wl[2 * ks], b0 = Wl[2 * ks + 1];
        plswap(a0, b0);
        const unsigned c0 = __shfl_xor(a0, 16), d0 = __shfl_xor(b0, 16);
        unsigned a1 = Wh[2 * ks], b1 = Wh[2 * ks + 1];
        plswap(a1, b1);
        const unsigned c1 = __shfl_xor(a1, 16), d1 = __shfl_xor(b1, 16);
        union { unsigned u[4]; bf16x8 v; } fr;
        fr.u[0] = odd ? d0 : a0;   // k-elems e0,e1 (group gA)
        fr.u[1] = odd ? d1 : a1;   // e2,e3 (gA)
        fr.u[2] = odd ? b0 : c0;   // e4,e5 (gB)
        fr.u[3] = odd ? b1 : c1;   // e6,e7 (gB)
        const bf16x8 v0 =
            *(const bf16x8*)&Vt[m16 * 328 + hh * 160 + ks * 32 + qd * 8];
        const bf16x8 v1 =
            *(const bf16x8*)&Vt[(16 + m16) * 328 + hh * 160 + ks * 32 + qd * 8];
        accO0 = __builtin_amdgcn_mfma_f32_16x16x32_bf16(fr.v, v0, accO0, 0, 0, 0);
        accO1 = __builtin_amdgcn_mfma_f32_16x16x32_bf16(fr.v, v1, accO1, 0, 0, 0);
      }
      __builtin_amdgcn_s_setprio(0);
    }

#pragma unroll
    for (int r = 0; r < 4; ++r) {
      const int j = jt * 16 + qd * 4 + r;
      const float g0 = bf2f(Gg[base + (size_t)j * 32 + m16]);
      const float g1 = bf2f(Gg[base + (size_t)j * 32 + 16 + m16]);
      unsigned short* op = Obg + (size_t)(i * 320 + j) * 128 + h * 32;
      op[m16]      = f2bf(g0 * rle[r] * accO0[r]);
      op[16 + m16] = f2bf(g1 * rle[r] * accO1[r]);
    }
  }
}

// ---------------------------------------------------------------------------
// Kernel 3: output GEMM dz = Obg @ Woutt^T, * pair_mask. bf16 MFMA.
// (unchanged)
// ---------------------------------------------------------------------------
__global__ __launch_bounds__(256) void k_out(
    const unsigned short* __restrict__ Obg, const unsigned short* __restrict__ Woutt,
    const float* __restrict__ pm, float* __restrict__ out)
{
  __shared__ __attribute__((aligned(16))) unsigned short As[128 * 136];
  __shared__ __attribute__((aligned(16))) unsigned short Bs[64 * 136];
  const int t = threadIdx.x;
  const int ntile = blockIdx.x;   // 0..1
  const int m0 = blockIdx.y * 128;

#pragma unroll
  for (int it = 0; it < 8; ++it) {
    const int idx = t + 256 * it;
    const int rr = idx >> 4, ck = idx & 15;
    const uint4 d = *(const uint4*)(Obg + (size_t)(m0 + rr) * 128 + ck * 8);
    *(uint4*)&As[rr * 136 + ck * 8] = d;
  }
  {
    const unsigned short* wrow = Woutt + (size_t)ntile * 64 * 128;
#pragma unroll
    for (int it = 0; it < 4; ++it) {
      const int idx = t + 256 * it;
      const int n = idx >> 4, ck = idx & 15;
      const uint4 d = *(const uint4*)(wrow + n * 128 + ck * 8);
      *(uint4*)&Bs[n * 136 + ck * 8] = d;
    }
  }
  __syncthreads();

  const int w = t >> 6, lane = t & 63;
  const int m16 = lane & 15, qd = lane >> 4;
  const f32x4 z4 = {0.f, 0.f, 0.f, 0.f};
  f32x4 acc[2][4];
#pragma unroll
  for (int sub = 0; sub < 2; ++sub)
#pragma unroll
    for (int nt = 0; nt < 4; ++nt) acc[sub][nt] = z4;

#pragma unroll
  for (int ks = 0; ks < 4; ++ks) {
    const bf16x8 af0 = *(const bf16x8*)&As[(w * 32 + m16) * 136 + qd * 8 + ks * 32];
    const bf16x8 af1 = *(const bf16x8*)&As[(w * 32 + 16 + m16) * 136 + qd * 8 + ks * 32];
#pragma unroll
    for (int nt = 0; nt < 4; ++nt) {
      const bf16x8 bf = *(const bf16x8*)&Bs[(nt * 16 + m16) * 136 + qd * 8 + ks * 32];
      acc[0][nt] = __builtin_amdgcn_mfma_f32_16x16x32_bf16(af0, bf, acc[0][nt], 0, 0, 0);
      acc[1][nt] = __builtin_amdgcn_mfma_f32_16x16x32_bf16(af1, bf, acc[1][nt], 0, 0, 0);
    }
  }

#pragma unroll
  for (int sub = 0; sub < 2; ++sub) {
#pragma unroll
    for (int r = 0; r < 4; ++r) {
      const int p = m0 + w * 32 + sub * 16 + qd * 4 + r;
      const float m = pm[p];
      float* orow = out + (size_t)p * 128 + ntile * 64;
#pragma unroll
      for (int nt = 0; nt < 4; ++nt)
        orow[nt * 16 + m16] = acc[sub][nt][r] * m;
    }
  }
}

// ---------------------------------------------------------------------------
extern "C" void kernel_launch(void* const* d_in, const int* in_sizes, int n_in,
                              void* d_out, int out_size, void* d_ws, size_t ws_size,
                              hipStream_t stream)
{
  const float* z     = (const float*)d_in[0];
  const float* pmask = (const float*)d_in[1];
  const int*   rmask = (const int*)d_in[2];
  const float* gamma = (const float*)d_in[3];
  const float* beta  = (const float*)d_in[4];
  const float* Wq    = (const float*)d_in[5];
  const float* Wk    = (const float*)d_in[6];
  const float* Wv    = (const float*)d_in[7];
  const float* Wb    = (const float*)d_in[8];
  const float* Wg    = (const float*)d_in[9];
  const float* Wout  = (const float*)d_in[10];

  const size_t P = (size_t)LDIM * LDIM;        // 102400
  const size_t E = P * 128;                    // 13,107,200 elements
  char* ws = (char*)d_ws;
  unsigned short* Qg = (unsigned short*)ws;              // E bf16
  unsigned short* Kg = Qg + E;
  unsigned short* Vg = Kg + E;
  unsigned short* Gg = Vg + E;
  unsigned short* Obg = Gg + E;                          // E bf16
  unsigned short* Wt = Obg + E;                          // 576*128 bf16
  unsigned short* Woutt = Wt + 576 * 128;                // 128*128 bf16
  float* Bh = (float*)(Woutt + 128 * 128);               // 4*P fp32

  k_prep<<<dim3(11), 256, 0, stream>>>(Wq, Wk, Wv, Wb, Wg, Wout, Wt, Woutt);
  k_lnproj<<<dim3(800), 256, 0, stream>>>(z, gamma, beta, Wt, rmask,
                                          Qg, Kg, Vg, Gg, Bh);
  k_attn<<<dim3(NH, LDIM), 256, 0, stream>>>(Qg, Kg, Vg, Gg, Bh, Obg);
  k_out<<<dim3(2, 800), 256, 0, stream>>>(Obg, Woutt, pmask, (float*)d_out);
}

// Round 4
// 356.455 us; speedup vs baseline: 1.0170x; 1.0170x over previous
//
#include <hip/hip_runtime.h>

#define LDIM 320
#define CZ 128
#define NH 4
#define CH 32
// SCALE * log2(e): softmax runs in exp2 domain
#define SCALE2F (0.17677669529663687f * 1.4426950408889634f)
#define LOG2E 1.4426950408889634f
#define LN_EPS 1e-5f

typedef __attribute__((ext_vector_type(8))) short bf16x8;
typedef __attribute__((ext_vector_type(4))) float f32x4;

__device__ __forceinline__ unsigned int pack_bf2(float a, float b) {
  unsigned int ua = __float_as_uint(a);
  unsigned int ub = __float_as_uint(b);
  unsigned int ra = (ua + 0x7fffu + ((ua >> 16) & 1u)) >> 16;   // RNE bf16
  unsigned int rb = (ub + 0x7fffu + ((ub >> 16) & 1u)) >> 16;
  return (ra & 0xffffu) | (rb << 16);
}

__device__ __forceinline__ unsigned short f2bf(float a) {
  unsigned int ua = __float_as_uint(a);
  return (unsigned short)((ua + 0x7fffu + ((ua >> 16) & 1u)) >> 16);
}

__device__ __forceinline__ float bf2f(unsigned short u) {
  return __uint_as_float(((unsigned int)u) << 16);
}

// v_cvt_pk_bf16_f32: lo16 = bf16(a), hi16 = bf16(b), RNE (no builtin on gfx950)
__device__ __forceinline__ unsigned cvtpk(float a, float b) {
  unsigned r;
  asm("v_cvt_pk_bf16_f32 %0, %1, %2" : "=v"(r) : "v"(a), "v"(b));
  return r;
}

// v_permlane32_swap_b32: swaps a.lanes[32..63] <-> b.lanes[0..31]
// After: a = [a.r0 a.r1 b.r0 b.r1], b = [a.r2 a.r3 b.r2 b.r3]  (r = 16-lane row)
__device__ __forceinline__ void plswap32(unsigned& a, unsigned& b) {
  asm volatile("v_permlane32_swap_b32 %0, %1" : "+v"(a), "+v"(b));
}

// v_permlane16_swap_b32: swaps a.r1<->b.r0 and a.r3<->b.r2
// After: a = [a.r0 b.r0 a.r2 b.r2], b = [a.r1 b.r1 a.r3 b.r3]
__device__ __forceinline__ void plswap16(unsigned& a, unsigned& b) {
  asm volatile("v_permlane16_swap_b32 %0, %1" : "+v"(a), "+v"(b));
}

// ---------------------------------------------------------------------------
// Kernel 0: weight prep. Wt[576][128] bf16 = [Wq|Wk|Wv|Wg|Wb|0] transposed;
// Woutt[128][128] bf16 = Wout transposed. Runs once per launch (11 blocks).
// ---------------------------------------------------------------------------
__global__ __launch_bounds__(256) void k_prep(
    const float* __restrict__ Wq, const float* __restrict__ Wk,
    const float* __restrict__ Wv, const float* __restrict__ Wb,
    const float* __restrict__ Wg, const float* __restrict__ Wout,
    unsigned short* __restrict__ Wt, unsigned short* __restrict__ Woutt)
{
  __shared__ __attribute__((aligned(16))) unsigned short buf[64 * 136];
  const int t = threadIdx.x, bid = blockIdx.x;
  const bool isOut = (bid >= 9);
  const int n0 = isOut ? (bid - 9) * 64 : bid * 64;
  const int nl = t & 63;
  const int n = n0 + nl;
#pragma unroll 8
  for (int it = 0; it < 32; ++it) {
    const int k = (t >> 6) + 4 * it;
    float v;
    if (isOut)        v = Wout[k * 128 + n];
    else if (n < 128) v = Wq[k * 128 + n];
    else if (n < 256) v = Wk[k * 128 + n - 128];
    else if (n < 384) v = Wv[k * 128 + n - 256];
    else if (n < 512) v = Wg[k * 128 + n - 384];
    else if (n < 516) v = Wb[k * 4 + n - 512];
    else              v = 0.f;
    buf[nl * 136 + k] = f2bf(v);
  }
  __syncthreads();
  unsigned short* dst = isOut ? Woutt : Wt;
#pragma unroll
  for (int it = 0; it < 4; ++it) {
    const int idx = t + 256 * it;
    const int rr = idx >> 4, ck = idx & 15;
    const uint4 d = *(const uint4*)&buf[rr * 136 + ck * 8];
    *(uint4*)(dst + (size_t)(n0 + rr) * 128 + ck * 8) = d;
  }
}

// ---------------------------------------------------------------------------
// Kernel 1: fused LayerNorm + all projections, bf16 MFMA GEMM.
// Bh stores bias * log2(e) + (res_mask ? 0 : -inf).
// B-tile rows n = ntile*64 + m16*4 + nt -> each thread's 4 nt-outputs are
// consecutive channels -> one uint2 store (verified round 3).
// ---------------------------------------------------------------------------
__global__ __launch_bounds__(256) void k_lnproj(
    const float* __restrict__ z, const float* __restrict__ gamma,
    const float* __restrict__ beta, const unsigned short* __restrict__ Wt,
    const int* __restrict__ rmask,
    unsigned short* __restrict__ Qg, unsigned short* __restrict__ Kg,
    unsigned short* __restrict__ Vg, unsigned short* __restrict__ Gg,
    float* __restrict__ Bh)
{
  __shared__ __attribute__((aligned(16))) unsigned short As[128 * 136]; // 34.8KB
  const int t = threadIdx.x;
  const int m0 = blockIdx.x * 128;
  const int rlane = t & 7;            // 8 lanes per row, 16 cols each

  const float* gp = gamma + rlane * 16;
  const float* bp = beta + rlane * 16;
  const float4 g0 = *(const float4*)(gp + 0);
  const float4 g1 = *(const float4*)(gp + 4);
  const float4 g2 = *(const float4*)(gp + 8);
  const float4 g3 = *(const float4*)(gp + 12);
  const float4 b0 = *(const float4*)(bp + 0);
  const float4 b1 = *(const float4*)(bp + 4);
  const float4 b2 = *(const float4*)(bp + 8);
  const float4 b3 = *(const float4*)(bp + 12);

  // ---- stage z -> LN -> bf16 As, coalesced (8 lanes/row) ----
#pragma unroll
  for (int rr = 0; rr < 4; ++rr) {
    const int row = rr * 32 + (t >> 3);
    const float* zp = z + (size_t)(m0 + row) * CZ + rlane * 16;
    const float4 x0 = *(const float4*)(zp + 0);
    const float4 x1 = *(const float4*)(zp + 4);
    const float4 x2 = *(const float4*)(zp + 8);
    const float4 x3 = *(const float4*)(zp + 12);
    float s  = x0.x + x0.y + x0.z + x0.w + x1.x + x1.y + x1.z + x1.w +
               x2.x + x2.y + x2.z + x2.w + x3.x + x3.y + x3.z + x3.w;
    float ss = x0.x*x0.x + x0.y*x0.y + x0.z*x0.z + x0.w*x0.w +
               x1.x*x1.x + x1.y*x1.y + x1.z*x1.z + x1.w*x1.w +
               x2.x*x2.x + x2.y*x2.y + x2.z*x2.z + x2.w*x2.w +
               x3.x*x3.x + x3.y*x3.y + x3.z*x3.z + x3.w*x3.w;
    s  += __shfl_xor(s, 1);  ss += __shfl_xor(ss, 1);
    s  += __shfl_xor(s, 2);  ss += __shfl_xor(ss, 2);
    s  += __shfl_xor(s, 4);  ss += __shfl_xor(ss, 4);
    const float mu  = s * (1.f / 128.f);
    const float var = ss * (1.f / 128.f) - mu * mu;
    const float rs  = rsqrtf(var + LN_EPS);
    uint4 u0, u1;
    u0.x = pack_bf2((x0.x - mu) * rs * g0.x + b0.x, (x0.y - mu) * rs * g0.y + b0.y);
    u0.y = pack_bf2((x0.z - mu) * rs * g0.z + b0.z, (x0.w - mu) * rs * g0.w + b0.w);
    u0.z = pack_bf2((x1.x - mu) * rs * g1.x + b1.x, (x1.y - mu) * rs * g1.y + b1.y);
    u0.w = pack_bf2((x1.z - mu) * rs * g1.z + b1.z, (x1.w - mu) * rs * g1.w + b1.w);
    u1.x = pack_bf2((x2.x - mu) * rs * g2.x + b2.x, (x2.y - mu) * rs * g2.y + b2.y);
    u1.y = pack_bf2((x2.z - mu) * rs * g2.z + b2.z, (x2.w - mu) * rs * g2.w + b2.w);
    u1.z = pack_bf2((x3.x - mu) * rs * g3.x + b3.x, (x3.y - mu) * rs * g3.y + b3.y);
    u1.w = pack_bf2((x3.z - mu) * rs * g3.z + b3.z, (x3.w - mu) * rs * g3.w + b3.w);
    unsigned short* dst = &As[row * 136 + rlane * 16];
    *(uint4*)(dst + 0) = u0;
    *(uint4*)(dst + 8) = u1;
  }
  __syncthreads();

  const int w = t >> 6, lane = t & 63;
  const int m16 = lane & 15, qd = lane >> 4;
  const f32x4 z4 = {0.f, 0.f, 0.f, 0.f};

  // ---- preload A-frags once (2 sub-tiles x 4 k-steps = 32 VGPRs) ----
  bf16x8 af[2][4];
#pragma unroll
  for (int ks = 0; ks < 4; ++ks) {
    af[0][ks] = *(const bf16x8*)&As[(w * 32 + m16) * 136 + ks * 32 + qd * 8];
    af[1][ks] = *(const bf16x8*)&As[(w * 32 + 16 + m16) * 136 + ks * 32 + qd * 8];
  }

  // ---- 8 output n-tiles (Q/K/V/G); B rows n = ntile*64 + m16*4 + nt ----
  for (int ntile = 0; ntile < 8; ++ntile) {
    f32x4 acc[2][4];
#pragma unroll
    for (int sub = 0; sub < 2; ++sub)
#pragma unroll
      for (int nt = 0; nt < 4; ++nt) acc[sub][nt] = z4;
#pragma unroll
    for (int ks = 0; ks < 4; ++ks) {
#pragma unroll
      for (int nt = 0; nt < 4; ++nt) {
        const bf16x8 bf = *(const bf16x8*)(
            Wt + (size_t)(ntile * 64 + m16 * 4 + nt) * 128 + ks * 32 + qd * 8);
        acc[0][nt] = __builtin_amdgcn_mfma_f32_16x16x32_bf16(af[0][ks], bf, acc[0][nt], 0, 0, 0);
        acc[1][nt] = __builtin_amdgcn_mfma_f32_16x16x32_bf16(af[1][ks], bf, acc[1][nt], 0, 0, 0);
      }
    }
    // epilogue: thread (sub,r) owns 4 consecutive channels cc0..cc0+3
    const int cc0 = (m16 * 4) & 31;
    const int hh = (ntile & 1) * 2 + (m16 >> 3);
    unsigned short* dstb =
        (ntile < 2 ? Qg : (ntile < 4 ? Kg : (ntile < 6 ? Vg : Gg)));
#pragma unroll
    for (int sub = 0; sub < 2; ++sub) {
#pragma unroll
      for (int r = 0; r < 4; ++r) {
        const int p = m0 + w * 32 + sub * 16 + qd * 4 + r;
        const int a = p / 320, bb = p - a * 320;
        float v0 = acc[sub][0][r], v1 = acc[sub][1][r];
        float v2 = acc[sub][2][r], v3 = acc[sub][3][r];
        if (ntile >= 6) {
          v0 = 1.f / (1.f + __expf(-v0));
          v1 = 1.f / (1.f + __expf(-v1));
          v2 = 1.f / (1.f + __expf(-v2));
          v3 = 1.f / (1.f + __expf(-v3));
        }
        uint2 pk;
        pk.x = pack_bf2(v0, v1);
        pk.y = pack_bf2(v2, v3);
        *(uint2*)(dstb + ((size_t)(a * 4 + hh) * 320 + bb) * 32 + cc0) = pk;
      }
    }
  }

  // ---- bias tile: store log2e-scaled bias with res_mask folded in ----
  {
    f32x4 acc0 = z4, acc1 = z4;
#pragma unroll
    for (int ks = 0; ks < 4; ++ks) {
      const bf16x8 bf = *(const bf16x8*)(
          Wt + (size_t)(512 + m16) * 128 + ks * 32 + qd * 8);
      acc0 = __builtin_amdgcn_mfma_f32_16x16x32_bf16(af[0][ks], bf, acc0, 0, 0, 0);
      acc1 = __builtin_amdgcn_mfma_f32_16x16x32_bf16(af[1][ks], bf, acc1, 0, 0, 0);
    }
    if (m16 < 4) {
#pragma unroll
      for (int r = 0; r < 4; ++r) {
        const int p0 = m0 + w * 32 + qd * 4 + r;
        const int p1 = p0 + 16;
        const float mk0 = rmask[p0 % 320] ? 0.f : -INFINITY;
        const float mk1 = rmask[p1 % 320] ? 0.f : -INFINITY;
        Bh[(size_t)m16 * 102400 + p0] = acc0[r] * LOG2E + mk0;
        Bh[(size_t)m16 * 102400 + p1] = acc1[r] * LOG2E + mk1;
      }
    }
  }
}

// ---------------------------------------------------------------------------
// Kernel 2: MFMA attention — register-space P transpose, VALU-only exchange.
// Swapped QK^T (acc = mfma(K, Q)): lane (qd,m16) holds S[k=kt*16+qd*4+r][j=m16].
// P -> A-frag per ks window: with X=Wl[2ks],Z=Wl[2ks+1] (rows = qd groups):
//   plswap32(X,Z): X=[X0 X1 Z0 Z1], Z=[X2 X3 Z2 Z3]
//   plswap16(X,Z): X=[X0 X2 Z0 Z2]=u0, Z=[X1 X3 Z1 Z3]=u2
// (identical data to round-3's verified shfl/cndmask table, but 4 VALU
// permlanes per ks instead of 4 ds_swizzle + 8 cndmask — no LDS latency.)
// ---------------------------------------------------------------------------
__global__ __launch_bounds__(256) void k_attn(
    const unsigned short* __restrict__ Qg, const unsigned short* __restrict__ Kg,
    const unsigned short* __restrict__ Vg, const unsigned short* __restrict__ Gg,
    const float* __restrict__ Bh, unsigned short* __restrict__ Obg)
{
  __shared__ __attribute__((aligned(16))) unsigned short Vt[32 * 328];  // [c][k] 21KB
  const int h = blockIdx.x, i = blockIdx.y;
  const int t = threadIdx.x;
  const size_t base = (size_t)(i * NH + h) * (LDIM * CH);

  // ---- stage V transposed [c][k] ----
  {
    const int k0 = t >> 3, c4 = (t & 7) * 4;
#pragma unroll
    for (int it = 0; it < 10; ++it) {
      const int k = k0 + 32 * it;
      const uint2 d = *(const uint2*)(Vg + base + k * 32 + c4);
      Vt[(c4 + 0) * 328 + k] = (unsigned short)(d.x & 0xffffu);
      Vt[(c4 + 1) * 328 + k] = (unsigned short)(d.x >> 16);
      Vt[(c4 + 2) * 328 + k] = (unsigned short)(d.y & 0xffffu);
      Vt[(c4 + 3) * 328 + k] = (unsigned short)(d.y >> 16);
    }
  }
  __syncthreads();   // only barrier in the kernel

  const int w = t >> 6, lane = t & 63;
  const int m16 = lane & 15, qd = lane >> 4;
  const f32x4 z4 = {0.f, 0.f, 0.f, 0.f};

  for (int jt = w; jt < 20; jt += 4) {
    const bf16x8 qfrag =
        *(const bf16x8*)(Qg + base + (size_t)(jt * 16 + m16) * 32 + qd * 8);

    f32x4 acc[20];
    __builtin_amdgcn_s_setprio(1);
#pragma unroll
    for (int kt = 0; kt < 20; ++kt) {
      const bf16x8 kf =
          *(const bf16x8*)(Kg + base + (size_t)(kt * 16 + m16) * 32 + qd * 8);
      acc[kt] = __builtin_amdgcn_mfma_f32_16x16x32_bf16(kf, qfrag, z4, 0, 0, 0);
    }
    __builtin_amdgcn_s_setprio(0);

    // Bh holds bias*log2e + mask(-inf); lane needs row j=jt*16+m16,
    // k = kt*16 + qd*4 + r -> one float4 per kt.
    const float* bq = Bh + (size_t)h * 102400 +
                      (size_t)(jt * 16 + m16) * 320 + qd * 4;
    float mxa = -INFINITY, mxb = -INFINITY;
#pragma unroll
    for (int kt = 0; kt < 20; ++kt) {
      const float4 bv = *(const float4*)(bq + kt * 16);
      const float s0 = fmaf(acc[kt][0], SCALE2F, bv.x);
      const float s1 = fmaf(acc[kt][1], SCALE2F, bv.y);
      const float s2 = fmaf(acc[kt][2], SCALE2F, bv.z);
      const float s3 = fmaf(acc[kt][3], SCALE2F, bv.w);
      acc[kt][0] = s0; acc[kt][1] = s1; acc[kt][2] = s2; acc[kt][3] = s3;
      mxa = fmaxf(mxa, fmaxf(s0, s1));
      mxb = fmaxf(mxb, fmaxf(s2, s3));
    }
    float mx = fmaxf(mxa, mxb);
    mx = fmaxf(mx, __shfl_xor(mx, 16));
    mx = fmaxf(mx, __shfl_xor(mx, 32));

    float l0 = 0.f, l1 = 0.f, l2 = 0.f, l3 = 0.f;
#pragma unroll
    for (int kt = 0; kt < 20; ++kt) {
      const float p0 = __builtin_amdgcn_exp2f(acc[kt][0] - mx);
      const float p1 = __builtin_amdgcn_exp2f(acc[kt][1] - mx);
      const float p2 = __builtin_amdgcn_exp2f(acc[kt][2] - mx);
      const float p3 = __builtin_amdgcn_exp2f(acc[kt][3] - mx);
      acc[kt][0] = p0; acc[kt][1] = p1; acc[kt][2] = p2; acc[kt][3] = p3;
      l0 += p0; l1 += p1; l2 += p2; l3 += p3;
    }
    float l = (l0 + l1) + (l2 + l3);
    l += __shfl_xor(l, 16);
    l += __shfl_xor(l, 32);
    const float rl = __builtin_amdgcn_rcpf(l);
    // redistribute: epilogue row j = jt*16 + qd*4 + r needs rl of that column
    float rle[4];
#pragma unroll
    for (int r = 0; r < 4; ++r) rle[r] = __shfl(rl, qd * 4 + r);

    f32x4 accO0 = z4, accO1 = z4;
#pragma unroll
    for (int hh = 0; hh < 2; ++hh) {
      // pack P~ (f32 -> bf16 pairs): Wl = k-offsets {0,1}, Wh = {2,3}
      unsigned Wl[10], Wh[10];
#pragma unroll
      for (int kr = 0; kr < 10; ++kr) {
        Wl[kr] = cvtpk(acc[hh * 10 + kr][0], acc[hh * 10 + kr][1]);
        Wh[kr] = cvtpk(acc[hh * 10 + kr][2], acc[hh * 10 + kr][3]);
      }
      __builtin_amdgcn_s_setprio(1);
#pragma unroll
      for (int ks = 0; ks < 5; ++ks) {
        unsigned x = Wl[2 * ks], zz = Wl[2 * ks + 1];
        plswap32(x, zz);
        plswap16(x, zz);          // x = u0 (k-elems e0,e1), zz = u2 (e4,e5)
        unsigned y = Wh[2 * ks], ww = Wh[2 * ks + 1];
        plswap32(y, ww);
        plswap16(y, ww);          // y = u1 (e2,e3), ww = u3 (e6,e7)
        union { unsigned u[4]; bf16x8 v; } fr;
        fr.u[0] = x;
        fr.u[1] = y;
        fr.u[2] = zz;
        fr.u[3] = ww;
        const bf16x8 v0 =
            *(const bf16x8*)&Vt[m16 * 328 + hh * 160 + ks * 32 + qd * 8];
        const bf16x8 v1 =
            *(const bf16x8*)&Vt[(16 + m16) * 328 + hh * 160 + ks * 32 + qd * 8];
        accO0 = __builtin_amdgcn_mfma_f32_16x16x32_bf16(fr.v, v0, accO0, 0, 0, 0);
        accO1 = __builtin_amdgcn_mfma_f32_16x16x32_bf16(fr.v, v1, accO1, 0, 0, 0);
      }
      __builtin_amdgcn_s_setprio(0);
    }

#pragma unroll
    for (int r = 0; r < 4; ++r) {
      const int j = jt * 16 + qd * 4 + r;
      const float g0 = bf2f(Gg[base + (size_t)j * 32 + m16]);
      const float g1 = bf2f(Gg[base + (size_t)j * 32 + 16 + m16]);
      unsigned short* op = Obg + (size_t)(i * 320 + j) * 128 + h * 32;
      op[m16]      = f2bf(g0 * rle[r] * accO0[r]);
      op[16 + m16] = f2bf(g1 * rle[r] * accO1[r]);
    }
  }
}

// ---------------------------------------------------------------------------
// Kernel 3: output GEMM dz = Obg @ Woutt^T, * pair_mask. bf16 MFMA.
// (unchanged)
// ---------------------------------------------------------------------------
__global__ __launch_bounds__(256) void k_out(
    const unsigned short* __restrict__ Obg, const unsigned short* __restrict__ Woutt,
    const float* __restrict__ pm, float* __restrict__ out)
{
  __shared__ __attribute__((aligned(16))) unsigned short As[128 * 136];
  __shared__ __attribute__((aligned(16))) unsigned short Bs[64 * 136];
  const int t = threadIdx.x;
  const int ntile = blockIdx.x;   // 0..1
  const int m0 = blockIdx.y * 128;

#pragma unroll
  for (int it = 0; it < 8; ++it) {
    const int idx = t + 256 * it;
    const int rr = idx >> 4, ck = idx & 15;
    const uint4 d = *(const uint4*)(Obg + (size_t)(m0 + rr) * 128 + ck * 8);
    *(uint4*)&As[rr * 136 + ck * 8] = d;
  }
  {
    const unsigned short* wrow = Woutt + (size_t)ntile * 64 * 128;
#pragma unroll
    for (int it = 0; it < 4; ++it) {
      const int idx = t + 256 * it;
      const int n = idx >> 4, ck = idx & 15;
      const uint4 d = *(const uint4*)(wrow + n * 128 + ck * 8);
      *(uint4*)&Bs[n * 136 + ck * 8] = d;
    }
  }
  __syncthreads();

  const int w = t >> 6, lane = t & 63;
  const int m16 = lane & 15, qd = lane >> 4;
  const f32x4 z4 = {0.f, 0.f, 0.f, 0.f};
  f32x4 acc[2][4];
#pragma unroll
  for (int sub = 0; sub < 2; ++sub)
#pragma unroll
    for (int nt = 0; nt < 4; ++nt) acc[sub][nt] = z4;

#pragma unroll
  for (int ks = 0; ks < 4; ++ks) {
    const bf16x8 af0 = *(const bf16x8*)&As[(w * 32 + m16) * 136 + qd * 8 + ks * 32];
    const bf16x8 af1 = *(const bf16x8*)&As[(w * 32 + 16 + m16) * 136 + qd * 8 + ks * 32];
#pragma unroll
    for (int nt = 0; nt < 4; ++nt) {
      const bf16x8 bf = *(const bf16x8*)&Bs[(nt * 16 + m16) * 136 + qd * 8 + ks * 32];
      acc[0][nt] = __builtin_amdgcn_mfma_f32_16x16x32_bf16(af0, bf, acc[0][nt], 0, 0, 0);
      acc[1][nt] = __builtin_amdgcn_mfma_f32_16x16x32_bf16(af1, bf, acc[1][nt], 0, 0, 0);
    }
  }

#pragma unroll
  for (int sub = 0; sub < 2; ++sub) {
#pragma unroll
    for (int r = 0; r < 4; ++r) {
      const int p = m0 + w * 32 + sub * 16 + qd * 4 + r;
      const float m = pm[p];
      float* orow = out + (size_t)p * 128 + ntile * 64;
#pragma unroll
      for (int nt = 0; nt < 4; ++nt)
        orow[nt * 16 + m16] = acc[sub][nt][r] * m;
    }
  }
}

// ---------------------------------------------------------------------------
extern "C" void kernel_launch(void* const* d_in, const int* in_sizes, int n_in,
                              void* d_out, int out_size, void* d_ws, size_t ws_size,
                              hipStream_t stream)
{
  const float* z     = (const float*)d_in[0];
  const float* pmask = (const float*)d_in[1];
  const int*   rmask = (const int*)d_in[2];
  const float* gamma = (const float*)d_in[3];
  const float* beta  = (const float*)d_in[4];
  const float* Wq    = (const float*)d_in[5];
  const float* Wk    = (const float*)d_in[6];
  const float* Wv    = (const float*)d_in[7];
  const float* Wb    = (const float*)d_in[8];
  const float* Wg    = (const float*)d_in[9];
  const float* Wout  = (const float*)d_in[10];

  const size_t P = (size_t)LDIM * LDIM;        // 102400
  const size_t E = P * 128;                    // 13,107,200 elements
  char* ws = (char*)d_ws;
  unsigned short* Qg = (unsigned short*)ws;              // E bf16
  unsigned short* Kg = Qg + E;
  unsigned short* Vg = Kg + E;
  unsigned short* Gg = Vg + E;
  unsigned short* Obg = Gg + E;                          // E bf16
  unsigned short* Wt = Obg + E;                          // 576*128 bf16
  unsigned short* Woutt = Wt + 576 * 128;                // 128*128 bf16
  float* Bh = (float*)(Woutt + 128 * 128);               // 4*P fp32

  k_prep<<<dim3(11), 256, 0, stream>>>(Wq, Wk, Wv, Wb, Wg, Wout, Wt, Woutt);
  k_lnproj<<<dim3(800), 256, 0, stream>>>(z, gamma, beta, Wt, rmask,
                                          Qg, Kg, Vg, Gg, Bh);
  k_attn<<<dim3(NH, LDIM), 256, 0, stream>>>(Qg, Kg, Vg, Gg, Bh, Obg);
  k_out<<<dim3(2, 800), 256, 0, stream>>>(Obg, Woutt, pmask, (float*)d_out);
}

// Round 5
// 340.654 us; speedup vs baseline: 1.0641x; 1.0464x over previous
//
#include <hip/hip_runtime.h>

#define LDIM 320
#define CZ 128
#define NH 4
#define CH 32
// SCALE * log2(e): softmax runs in exp2 domain
#define SCALE2F (0.17677669529663687f * 1.4426950408889634f)
#define LOG2E 1.4426950408889634f
#define LN_EPS 1e-5f

typedef __attribute__((ext_vector_type(8))) short bf16x8;
typedef __attribute__((ext_vector_type(4))) float f32x4;

__device__ __forceinline__ unsigned int pack_bf2(float a, float b) {
  unsigned int ua = __float_as_uint(a);
  unsigned int ub = __float_as_uint(b);
  unsigned int ra = (ua + 0x7fffu + ((ua >> 16) & 1u)) >> 16;   // RNE bf16
  unsigned int rb = (ub + 0x7fffu + ((ub >> 16) & 1u)) >> 16;
  return (ra & 0xffffu) | (rb << 16);
}

__device__ __forceinline__ unsigned short f2bf(float a) {
  unsigned int ua = __float_as_uint(a);
  return (unsigned short)((ua + 0x7fffu + ((ua >> 16) & 1u)) >> 16);
}

__device__ __forceinline__ float bf2f(unsigned short u) {
  return __uint_as_float(((unsigned int)u) << 16);
}

// v_cvt_pk_bf16_f32: lo16 = bf16(a), hi16 = bf16(b), RNE (no builtin on gfx950)
__device__ __forceinline__ unsigned cvtpk(float a, float b) {
  unsigned r;
  asm("v_cvt_pk_bf16_f32 %0, %1, %2" : "=v"(r) : "v"(a), "v"(b));
  return r;
}

// ---------------------------------------------------------------------------
// Kernel 0: weight prep. Wt[576][128] bf16 = [Wq|Wk|Wv|Wg|Wb|0] transposed;
// Woutt[128][128] bf16 = Wout transposed. Runs once per launch (11 blocks).
// ---------------------------------------------------------------------------
__global__ __launch_bounds__(256) void k_prep(
    const float* __restrict__ Wq, const float* __restrict__ Wk,
    const float* __restrict__ Wv, const float* __restrict__ Wb,
    const float* __restrict__ Wg, const float* __restrict__ Wout,
    unsigned short* __restrict__ Wt, unsigned short* __restrict__ Woutt)
{
  __shared__ __attribute__((aligned(16))) unsigned short buf[64 * 136];
  const int t = threadIdx.x, bid = blockIdx.x;
  const bool isOut = (bid >= 9);
  const int n0 = isOut ? (bid - 9) * 64 : bid * 64;
  const int nl = t & 63;
  const int n = n0 + nl;
#pragma unroll 8
  for (int it = 0; it < 32; ++it) {
    const int k = (t >> 6) + 4 * it;
    float v;
    if (isOut)        v = Wout[k * 128 + n];
    else if (n < 128) v = Wq[k * 128 + n];
    else if (n < 256) v = Wk[k * 128 + n - 128];
    else if (n < 384) v = Wv[k * 128 + n - 256];
    else if (n < 512) v = Wg[k * 128 + n - 384];
    else if (n < 516) v = Wb[k * 4 + n - 512];
    else              v = 0.f;
    buf[nl * 136 + k] = f2bf(v);
  }
  __syncthreads();
  unsigned short* dst = isOut ? Woutt : Wt;
#pragma unroll
  for (int it = 0; it < 4; ++it) {
    const int idx = t + 256 * it;
    const int rr = idx >> 4, ck = idx & 15;
    const uint4 d = *(const uint4*)&buf[rr * 136 + ck * 8];
    *(uint4*)(dst + (size_t)(n0 + rr) * 128 + ck * 8) = d;
  }
}

// ---------------------------------------------------------------------------
// Kernel 1: fused LayerNorm + all projections, bf16 MFMA GEMM.
// Bh stores bias * log2(e) + (res_mask ? 0 : -inf).
// B-tile rows n = ntile*64 + m16*4 + nt -> uint2 stores (verified round 3).
// ---------------------------------------------------------------------------
__global__ __launch_bounds__(256) void k_lnproj(
    const float* __restrict__ z, const float* __restrict__ gamma,
    const float* __restrict__ beta, const unsigned short* __restrict__ Wt,
    const int* __restrict__ rmask,
    unsigned short* __restrict__ Qg, unsigned short* __restrict__ Kg,
    unsigned short* __restrict__ Vg, unsigned short* __restrict__ Gg,
    float* __restrict__ Bh)
{
  __shared__ __attribute__((aligned(16))) unsigned short As[128 * 136]; // 34.8KB
  const int t = threadIdx.x;
  const int m0 = blockIdx.x * 128;
  const int rlane = t & 7;            // 8 lanes per row, 16 cols each

  const float* gp = gamma + rlane * 16;
  const float* bp = beta + rlane * 16;
  const float4 g0 = *(const float4*)(gp + 0);
  const float4 g1 = *(const float4*)(gp + 4);
  const float4 g2 = *(const float4*)(gp + 8);
  const float4 g3 = *(const float4*)(gp + 12);
  const float4 b0 = *(const float4*)(bp + 0);
  const float4 b1 = *(const float4*)(bp + 4);
  const float4 b2 = *(const float4*)(bp + 8);
  const float4 b3 = *(const float4*)(bp + 12);

  // ---- stage z -> LN -> bf16 As, coalesced (8 lanes/row) ----
#pragma unroll
  for (int rr = 0; rr < 4; ++rr) {
    const int row = rr * 32 + (t >> 3);
    const float* zp = z + (size_t)(m0 + row) * CZ + rlane * 16;
    const float4 x0 = *(const float4*)(zp + 0);
    const float4 x1 = *(const float4*)(zp + 4);
    const float4 x2 = *(const float4*)(zp + 8);
    const float4 x3 = *(const float4*)(zp + 12);
    float s  = x0.x + x0.y + x0.z + x0.w + x1.x + x1.y + x1.z + x1.w +
               x2.x + x2.y + x2.z + x2.w + x3.x + x3.y + x3.z + x3.w;
    float ss = x0.x*x0.x + x0.y*x0.y + x0.z*x0.z + x0.w*x0.w +
               x1.x*x1.x + x1.y*x1.y + x1.z*x1.z + x1.w*x1.w +
               x2.x*x2.x + x2.y*x2.y + x2.z*x2.z + x2.w*x2.w +
               x3.x*x3.x + x3.y*x3.y + x3.z*x3.z + x3.w*x3.w;
    s  += __shfl_xor(s, 1);  ss += __shfl_xor(ss, 1);
    s  += __shfl_xor(s, 2);  ss += __shfl_xor(ss, 2);
    s  += __shfl_xor(s, 4);  ss += __shfl_xor(ss, 4);
    const float mu  = s * (1.f / 128.f);
    const float var = ss * (1.f / 128.f) - mu * mu;
    const float rs  = rsqrtf(var + LN_EPS);
    uint4 u0, u1;
    u0.x = pack_bf2((x0.x - mu) * rs * g0.x + b0.x, (x0.y - mu) * rs * g0.y + b0.y);
    u0.y = pack_bf2((x0.z - mu) * rs * g0.z + b0.z, (x0.w - mu) * rs * g0.w + b0.w);
    u0.z = pack_bf2((x1.x - mu) * rs * g1.x + b1.x, (x1.y - mu) * rs * g1.y + b1.y);
    u0.w = pack_bf2((x1.z - mu) * rs * g1.z + b1.z, (x1.w - mu) * rs * g1.w + b1.w);
    u1.x = pack_bf2((x2.x - mu) * rs * g2.x + b2.x, (x2.y - mu) * rs * g2.y + b2.y);
    u1.y = pack_bf2((x2.z - mu) * rs * g2.z + b2.z, (x2.w - mu) * rs * g2.w + b2.w);
    u1.z = pack_bf2((x3.x - mu) * rs * g3.x + b3.x, (x3.y - mu) * rs * g3.y + b3.y);
    u1.w = pack_bf2((x3.z - mu) * rs * g3.z + b3.z, (x3.w - mu) * rs * g3.w + b3.w);
    unsigned short* dst = &As[row * 136 + rlane * 16];
    *(uint4*)(dst + 0) = u0;
    *(uint4*)(dst + 8) = u1;
  }
  __syncthreads();

  const int w = t >> 6, lane = t & 63;
  const int m16 = lane & 15, qd = lane >> 4;
  const f32x4 z4 = {0.f, 0.f, 0.f, 0.f};

  // ---- preload A-frags once (2 sub-tiles x 4 k-steps = 32 VGPRs) ----
  bf16x8 af[2][4];
#pragma unroll
  for (int ks = 0; ks < 4; ++ks) {
    af[0][ks] = *(const bf16x8*)&As[(w * 32 + m16) * 136 + ks * 32 + qd * 8];
    af[1][ks] = *(const bf16x8*)&As[(w * 32 + 16 + m16) * 136 + ks * 32 + qd * 8];
  }

  // ---- 8 output n-tiles (Q/K/V/G); B rows n = ntile*64 + m16*4 + nt ----
  for (int ntile = 0; ntile < 8; ++ntile) {
    f32x4 acc[2][4];
#pragma unroll
    for (int sub = 0; sub < 2; ++sub)
#pragma unroll
      for (int nt = 0; nt < 4; ++nt) acc[sub][nt] = z4;
#pragma unroll
    for (int ks = 0; ks < 4; ++ks) {
#pragma unroll
      for (int nt = 0; nt < 4; ++nt) {
        const bf16x8 bf = *(const bf16x8*)(
            Wt + (size_t)(ntile * 64 + m16 * 4 + nt) * 128 + ks * 32 + qd * 8);
        acc[0][nt] = __builtin_amdgcn_mfma_f32_16x16x32_bf16(af[0][ks], bf, acc[0][nt], 0, 0, 0);
        acc[1][nt] = __builtin_amdgcn_mfma_f32_16x16x32_bf16(af[1][ks], bf, acc[1][nt], 0, 0, 0);
      }
    }
    // epilogue: thread (sub,r) owns 4 consecutive channels cc0..cc0+3
    const int cc0 = (m16 * 4) & 31;
    const int hh = (ntile & 1) * 2 + (m16 >> 3);
    unsigned short* dstb =
        (ntile < 2 ? Qg : (ntile < 4 ? Kg : (ntile < 6 ? Vg : Gg)));
#pragma unroll
    for (int sub = 0; sub < 2; ++sub) {
#pragma unroll
      for (int r = 0; r < 4; ++r) {
        const int p = m0 + w * 32 + sub * 16 + qd * 4 + r;
        const int a = p / 320, bb = p - a * 320;
        float v0 = acc[sub][0][r], v1 = acc[sub][1][r];
        float v2 = acc[sub][2][r], v3 = acc[sub][3][r];
        if (ntile >= 6) {
          v0 = 1.f / (1.f + __expf(-v0));
          v1 = 1.f / (1.f + __expf(-v1));
          v2 = 1.f / (1.f + __expf(-v2));
          v3 = 1.f / (1.f + __expf(-v3));
        }
        uint2 pk;
        pk.x = pack_bf2(v0, v1);
        pk.y = pack_bf2(v2, v3);
        *(uint2*)(dstb + ((size_t)(a * 4 + hh) * 320 + bb) * 32 + cc0) = pk;
      }
    }
  }

  // ---- bias tile: store log2e-scaled bias with res_mask folded in ----
  {
    f32x4 acc0 = z4, acc1 = z4;
#pragma unroll
    for (int ks = 0; ks < 4; ++ks) {
      const bf16x8 bf = *(const bf16x8*)(
          Wt + (size_t)(512 + m16) * 128 + ks * 32 + qd * 8);
      acc0 = __builtin_amdgcn_mfma_f32_16x16x32_bf16(af[0][ks], bf, acc0, 0, 0, 0);
      acc1 = __builtin_amdgcn_mfma_f32_16x16x32_bf16(af[1][ks], bf, acc1, 0, 0, 0);
    }
    if (m16 < 4) {
#pragma unroll
      for (int r = 0; r < 4; ++r) {
        const int p0 = m0 + w * 32 + qd * 4 + r;
        const int p1 = p0 + 16;
        const float mk0 = rmask[p0 % 320] ? 0.f : -INFINITY;
        const float mk1 = rmask[p1 % 320] ? 0.f : -INFINITY;
        Bh[(size_t)m16 * 102400 + p0] = acc0[r] * LOG2E + mk0;
        Bh[(size_t)m16 * 102400 + p1] = acc1[r] * LOG2E + mk1;
      }
    }
  }
}

// ---------------------------------------------------------------------------
// Kernel 2: MFMA attention — swapped QK^T AND swapped PV, Ps LDS roundtrip.
// acc[kt] = mfma(kf, qfrag): lane (qd,m16) holds S[k=kt*16+qd*4+r][j=jt*16+m16]
//   -> float4 bias loads, in-lane softmax (ILP-4 chains + xor16/xor32),
//      per-j rl stays IN-LANE for the swapped-PV epilogue.
// P~ -> Ps[j=m16][k]: one ds_write_b64 per kt (cvtpk pairs); read back with
//   the round-0/2-verified b128 pattern Ps[m16*168 + ks*32 + qd*8].
// PV swapped: accO = mfma(v_frag, p_frag) -> D[c=qd*4+r][j=m16]; epilogue is
//   2 uint2 gate loads + 2 uint2 stores (was 8 scalar loads + 8 scalar stores
//   + 4 rl shuffles).
// No barriers in the main loop (Ps per-wave private; per-wave DS in-order).
// ---------------------------------------------------------------------------
__global__ __launch_bounds__(256) void k_attn(
    const unsigned short* __restrict__ Qg, const unsigned short* __restrict__ Kg,
    const unsigned short* __restrict__ Vg, const unsigned short* __restrict__ Gg,
    const float* __restrict__ Bh, unsigned short* __restrict__ Obg)
{
  __shared__ __attribute__((aligned(16))) unsigned short Vt[32 * 328];     // [c][k] 21KB
  __shared__ __attribute__((aligned(16))) unsigned short Ps[4][16 * 168];  // per-wave 21.5KB
  const int h = blockIdx.x, i = blockIdx.y;
  const int t = threadIdx.x;
  const size_t base = (size_t)(i * NH + h) * (LDIM * CH);

  // ---- stage V transposed [c][k] ----
  {
    const int k0 = t >> 3, c4 = (t & 7) * 4;
#pragma unroll
    for (int it = 0; it < 10; ++it) {
      const int k = k0 + 32 * it;
      const uint2 d = *(const uint2*)(Vg + base + k * 32 + c4);
      Vt[(c4 + 0) * 328 + k] = (unsigned short)(d.x & 0xffffu);
      Vt[(c4 + 1) * 328 + k] = (unsigned short)(d.x >> 16);
      Vt[(c4 + 2) * 328 + k] = (unsigned short)(d.y & 0xffffu);
      Vt[(c4 + 3) * 328 + k] = (unsigned short)(d.y >> 16);
    }
  }
  __syncthreads();   // only barrier in the kernel

  const int w = t >> 6, lane = t & 63;
  const int m16 = lane & 15, qd = lane >> 4;
  const f32x4 z4 = {0.f, 0.f, 0.f, 0.f};

  for (int jt = w; jt < 20; jt += 4) {
    const bf16x8 qfrag =
        *(const bf16x8*)(Qg + base + (size_t)(jt * 16 + m16) * 32 + qd * 8);

    f32x4 acc[20];
    __builtin_amdgcn_s_setprio(1);
#pragma unroll
    for (int kt = 0; kt < 20; ++kt) {
      const bf16x8 kf =
          *(const bf16x8*)(Kg + base + (size_t)(kt * 16 + m16) * 32 + qd * 8);
      acc[kt] = __builtin_amdgcn_mfma_f32_16x16x32_bf16(kf, qfrag, z4, 0, 0, 0);
    }
    __builtin_amdgcn_s_setprio(0);

    // Bh holds bias*log2e + mask(-inf); lane needs row j=jt*16+m16,
    // k = kt*16 + qd*4 + r -> one float4 per kt.
    const float* bq = Bh + (size_t)h * 102400 +
                      (size_t)(jt * 16 + m16) * 320 + qd * 4;
    float mx[4] = {-INFINITY, -INFINITY, -INFINITY, -INFINITY};
#pragma unroll
    for (int kt = 0; kt < 20; ++kt) {
      const float4 bv = *(const float4*)(bq + kt * 16);
      const float s0 = fmaf(acc[kt][0], SCALE2F, bv.x);
      const float s1 = fmaf(acc[kt][1], SCALE2F, bv.y);
      const float s2 = fmaf(acc[kt][2], SCALE2F, bv.z);
      const float s3 = fmaf(acc[kt][3], SCALE2F, bv.w);
      acc[kt][0] = s0; acc[kt][1] = s1; acc[kt][2] = s2; acc[kt][3] = s3;
      mx[0] = fmaxf(mx[0], s0);
      mx[1] = fmaxf(mx[1], s1);
      mx[2] = fmaxf(mx[2], s2);
      mx[3] = fmaxf(mx[3], s3);
    }
    float mxx = fmaxf(fmaxf(mx[0], mx[1]), fmaxf(mx[2], mx[3]));
    mxx = fmaxf(mxx, __shfl_xor(mxx, 16));
    mxx = fmaxf(mxx, __shfl_xor(mxx, 32));

    float l0 = 0.f, l1 = 0.f, l2 = 0.f, l3 = 0.f;
#pragma unroll
    for (int kt = 0; kt < 20; ++kt) {
      const float p0 = __builtin_amdgcn_exp2f(acc[kt][0] - mxx);
      const float p1 = __builtin_amdgcn_exp2f(acc[kt][1] - mxx);
      const float p2 = __builtin_amdgcn_exp2f(acc[kt][2] - mxx);
      const float p3 = __builtin_amdgcn_exp2f(acc[kt][3] - mxx);
      acc[kt][0] = p0; acc[kt][1] = p1; acc[kt][2] = p2; acc[kt][3] = p3;
      l0 += p0; l1 += p1; l2 += p2; l3 += p3;
    }
    float l = (l0 + l1) + (l2 + l3);
    l += __shfl_xor(l, 16);
    l += __shfl_xor(l, 32);
    const float rl = __builtin_amdgcn_rcpf(l);   // per-j (j=jt*16+m16), in-lane

    f32x4 accO0 = z4, accO1 = z4;
#pragma unroll
    for (int hh = 0; hh < 2; ++hh) {
      // ---- P~ -> Ps[j=m16][k-local]: one b64 write per kt (4 consec k) ----
#pragma unroll
      for (int kt2 = 0; kt2 < 10; ++kt2) {
        const int kt = hh * 10 + kt2;
        uint2 wv;
        wv.x = cvtpk(acc[kt][0], acc[kt][1]);
        wv.y = cvtpk(acc[kt][2], acc[kt][3]);
        *(uint2*)&Ps[w][m16 * 168 + kt2 * 16 + qd * 4] = wv;
      }
      __builtin_amdgcn_s_setprio(1);
#pragma unroll
      for (int ks = 0; ks < 5; ++ks) {
        const bf16x8 pf = *(const bf16x8*)&Ps[w][m16 * 168 + ks * 32 + qd * 8];
        const bf16x8 v0 =
            *(const bf16x8*)&Vt[m16 * 328 + hh * 160 + ks * 32 + qd * 8];
        const bf16x8 v1 =
            *(const bf16x8*)&Vt[(16 + m16) * 328 + hh * 160 + ks * 32 + qd * 8];
        accO0 = __builtin_amdgcn_mfma_f32_16x16x32_bf16(v0, pf, accO0, 0, 0, 0);
        accO1 = __builtin_amdgcn_mfma_f32_16x16x32_bf16(v1, pf, accO1, 0, 0, 0);
      }
      __builtin_amdgcn_s_setprio(0);
    }

    // ---- epilogue: accO0[r] = O[c=qd*4+r][j], accO1[r] = O[16+qd*4+r][j] ----
    {
      const int j = jt * 16 + m16;
      const uint2 gg0 = *(const uint2*)(Gg + base + (size_t)j * 32 + qd * 4);
      const uint2 gg1 = *(const uint2*)(Gg + base + (size_t)j * 32 + 16 + qd * 4);
      const float ga0 = bf2f((unsigned short)(gg0.x & 0xffffu));
      const float ga1 = bf2f((unsigned short)(gg0.x >> 16));
      const float ga2 = bf2f((unsigned short)(gg0.y & 0xffffu));
      const float ga3 = bf2f((unsigned short)(gg0.y >> 16));
      const float gb0 = bf2f((unsigned short)(gg1.x & 0xffffu));
      const float gb1 = bf2f((unsigned short)(gg1.x >> 16));
      const float gb2 = bf2f((unsigned short)(gg1.y & 0xffffu));
      const float gb3 = bf2f((unsigned short)(gg1.y >> 16));
      unsigned short* op = Obg + (size_t)(i * 320 + j) * 128 + h * 32;
      uint2 o0, o1;
      o0.x = cvtpk(ga0 * rl * accO0[0], ga1 * rl * accO0[1]);
      o0.y = cvtpk(ga2 * rl * accO0[2], ga3 * rl * accO0[3]);
      o1.x = cvtpk(gb0 * rl * accO1[0], gb1 * rl * accO1[1]);
      o1.y = cvtpk(gb2 * rl * accO1[2], gb3 * rl * accO1[3]);
      *(uint2*)(op + qd * 4) = o0;
      *(uint2*)(op + 16 + qd * 4) = o1;
    }
  }
}

// ---------------------------------------------------------------------------
// Kernel 3: output GEMM dz = Obg @ Woutt^T, * pair_mask. bf16 MFMA.
// (unchanged)
// ---------------------------------------------------------------------------
__global__ __launch_bounds__(256) void k_out(
    const unsigned short* __restrict__ Obg, const unsigned short* __restrict__ Woutt,
    const float* __restrict__ pm, float* __restrict__ out)
{
  __shared__ __attribute__((aligned(16))) unsigned short As[128 * 136];
  __shared__ __attribute__((aligned(16))) unsigned short Bs[64 * 136];
  const int t = threadIdx.x;
  const int ntile = blockIdx.x;   // 0..1
  const int m0 = blockIdx.y * 128;

#pragma unroll
  for (int it = 0; it < 8; ++it) {
    const int idx = t + 256 * it;
    const int rr = idx >> 4, ck = idx & 15;
    const uint4 d = *(const uint4*)(Obg + (size_t)(m0 + rr) * 128 + ck * 8);
    *(uint4*)&As[rr * 136 + ck * 8] = d;
  }
  {
    const unsigned short* wrow = Woutt + (size_t)ntile * 64 * 128;
#pragma unroll
    for (int it = 0; it < 4; ++it) {
      const int idx = t + 256 * it;
      const int n = idx >> 4, ck = idx & 15;
      const uint4 d = *(const uint4*)(wrow + n * 128 + ck * 8);
      *(uint4*)&Bs[n * 136 + ck * 8] = d;
    }
  }
  __syncthreads();

  const int w = t >> 6, lane = t & 63;
  const int m16 = lane & 15, qd = lane >> 4;
  const f32x4 z4 = {0.f, 0.f, 0.f, 0.f};
  f32x4 acc[2][4];
#pragma unroll
  for (int sub = 0; sub < 2; ++sub)
#pragma unroll
    for (int nt = 0; nt < 4; ++nt) acc[sub][nt] = z4;

#pragma unroll
  for (int ks = 0; ks < 4; ++ks) {
    const bf16x8 af0 = *(const bf16x8*)&As[(w * 32 + m16) * 136 + qd * 8 + ks * 32];
    const bf16x8 af1 = *(const bf16x8*)&As[(w * 32 + 16 + m16) * 136 + qd * 8 + ks * 32];
#pragma unroll
    for (int nt = 0; nt < 4; ++nt) {
      const bf16x8 bf = *(const bf16x8*)&Bs[(nt * 16 + m16) * 136 + qd * 8 + ks * 32];
      acc[0][nt] = __builtin_amdgcn_mfma_f32_16x16x32_bf16(af0, bf, acc[0][nt], 0, 0, 0);
      acc[1][nt] = __builtin_amdgcn_mfma_f32_16x16x32_bf16(af1, bf, acc[1][nt], 0, 0, 0);
    }
  }

#pragma unroll
  for (int sub = 0; sub < 2; ++sub) {
#pragma unroll
    for (int r = 0; r < 4; ++r) {
      const int p = m0 + w * 32 + sub * 16 + qd * 4 + r;
      const float m = pm[p];
      float* orow = out + (size_t)p * 128 + ntile * 64;
#pragma unroll
      for (int nt = 0; nt < 4; ++nt)
        orow[nt * 16 + m16] = acc[sub][nt][r] * m;
    }
  }
}

// ---------------------------------------------------------------------------
extern "C" void kernel_launch(void* const* d_in, const int* in_sizes, int n_in,
                              void* d_out, int out_size, void* d_ws, size_t ws_size,
                              hipStream_t stream)
{
  const float* z     = (const float*)d_in[0];
  const float* pmask = (const float*)d_in[1];
  const int*   rmask = (const int*)d_in[2];
  const float* gamma = (const float*)d_in[3];
  const float* beta  = (const float*)d_in[4];
  const float* Wq    = (const float*)d_in[5];
  const float* Wk    = (const float*)d_in[6];
  const float* Wv    = (const float*)d_in[7];
  const float* Wb    = (const float*)d_in[8];
  const float* Wg    = (const float*)d_in[9];
  const float* Wout  = (const float*)d_in[10];

  const size_t P = (size_t)LDIM * LDIM;        // 102400
  const size_t E = P * 128;                    // 13,107,200 elements
  char* ws = (char*)d_ws;
  unsigned short* Qg = (unsigned short*)ws;              // E bf16
  unsigned short* Kg = Qg + E;
  unsigned short* Vg = Kg + E;
  unsigned short* Gg = Vg + E;
  unsigned short* Obg = Gg + E;                          // E bf16
  unsigned short* Wt = Obg + E;                          // 576*128 bf16
  unsigned short* Woutt = Wt + 576 * 128;                // 128*128 bf16
  float* Bh = (float*)(Woutt + 128 * 128);               // 4*P fp32

  k_prep<<<dim3(11), 256, 0, stream>>>(Wq, Wk, Wv, Wb, Wg, Wout, Wt, Woutt);
  k_lnproj<<<dim3(800), 256, 0, stream>>>(z, gamma, beta, Wt, rmask,
                                          Qg, Kg, Vg, Gg, Bh);
  k_attn<<<dim3(NH, LDIM), 256, 0, stream>>>(Qg, Kg, Vg, Gg, Bh, Obg);
  k_out<<<dim3(2, 800), 256, 0, stream>>>(Obg, Woutt, pmask, (float*)d_out);
}